// Round 2
// baseline (437.263 us; speedup 1.0000x reference)
//
#include <hip/hip_runtime.h>
#include <math.h>

#define NB 8
#define NN 2048
#define IN_DIM 256
#define OUT_DIM 64
#define ALPHA 0.2f
#define IT 32
#define JT 64
#define JSPLIT 4

// ---------------------------------------------------------------------------
// Kernel 1: Wh = h @ W, s1 = Wh@a1, s2 = Wh@a2.  No LDS: h-row pointers are
// wave-uniform (readfirstlane) so h loads scalarize to s_load (SMEM pipe);
// W loads are coalesced and L2-hot. 16 rows/block, grid 1024.
// ---------------------------------------------------------------------------
__global__ __launch_bounds__(256) void wh_kernel(const float* __restrict__ h,
                                                 const float* __restrict__ W,
                                                 const float* __restrict__ a,
                                                 float* __restrict__ Wh,
                                                 float* __restrict__ s1,
                                                 float* __restrict__ s2) {
    const int t = threadIdx.x;
    const int d = t & 63;
    const int wv = __builtin_amdgcn_readfirstlane(t >> 6);
    const int rbase = blockIdx.x * 16 + wv;          // rows rbase + 4r
    const float* __restrict__ h0 = h + (long)rbase * IN_DIM;

    float acc[4] = {0.f, 0.f, 0.f, 0.f};
    #pragma unroll 4
    for (int k = 0; k < IN_DIM; k += 4) {
        // coalesced, L2-hot (W is 64 KB, reused by every block)
        const float w0 = W[(k + 0) * OUT_DIM + d];
        const float w1 = W[(k + 1) * OUT_DIM + d];
        const float w2 = W[(k + 2) * OUT_DIM + d];
        const float w3 = W[(k + 3) * OUT_DIM + d];
        #pragma unroll
        for (int r = 0; r < 4; ++r) {
            // uniform address -> s_load_dwordx4 (scalar cache, no VALU/VMEM)
            const float4 h4 = *(const float4*)(h0 + (long)(4 * r) * IN_DIM + k);
            acc[r] += h4.x * w0 + h4.y * w1 + h4.z * w2 + h4.w * w3;
        }
    }

    const float a1d = a[d];
    const float a2d = a[OUT_DIM + d];
    #pragma unroll
    for (int r = 0; r < 4; ++r) {
        const int grow = rbase + 4 * r;
        Wh[(long)grow * OUT_DIM + d] = acc[r];
        float v1 = acc[r] * a1d;
        float v2 = acc[r] * a2d;
        #pragma unroll
        for (int off = 32; off > 0; off >>= 1) {
            v1 += __shfl_xor(v1, off, 64);
            v2 += __shfl_xor(v2, off, 64);
        }
        if (d == 0) { s1[grow] = v1; s2[grow] = v2; }
    }
}

// ---------------------------------------------------------------------------
// Kernel 2: fused masked-softmax + P@Wh, no max subtraction (scores bounded).
// 4-way j-split: grid NB*64*JSPLIT = 2048 blocks (8/CU), partials accumulated
// into out (f32 atomics) + l; finalize kernel divides.
//  Phase A: lane=j streams adj, p -> LDS (stride 64; writes 2-way = free),
//           l accumulated in registers (no per-tile shuffles).
//  Phase B: 2 rows x 4 cols/thread; p via ds_read_b128 broadcast, Wh float4.
// ---------------------------------------------------------------------------
__global__ __launch_bounds__(256) void attn_kernel(const int* __restrict__ adj,
                                                   const float* __restrict__ Wh,
                                                   const float* __restrict__ s1,
                                                   const float* __restrict__ s2,
                                                   float* __restrict__ out,
                                                   float* __restrict__ l) {
    __shared__ float p_lds[IT * JT];   // 8 KB
    __shared__ float s1_lds[IT];

    const int t = threadIdx.x;
    const int bid = blockIdx.x;
    const int js = bid & (JSPLIT - 1);
    const int it = (bid >> 2) & 63;
    const int b = bid >> 8;
    const int i0 = it * IT;

    if (t < IT) s1_lds[t] = s1[b * NN + i0 + t];
    __syncthreads();

    const int lane = t & 63;
    const int wv = t >> 6;
    const int r0 = (t >> 4) << 1;             // phase-B rows r0, r0+1
    const int d0 = (t & 15) << 2;             // phase-B cols d0..d0+3

    float acc0[4] = {0.f, 0.f, 0.f, 0.f};
    float acc1[4] = {0.f, 0.f, 0.f, 0.f};
    float lacc[8] = {0.f, 0.f, 0.f, 0.f, 0.f, 0.f, 0.f, 0.f};

    const long adj_base = (long)b * NN * NN + (long)i0 * NN;
    const float* WhB = Wh + (long)b * NN * OUT_DIM;
    const float* s2B = s2 + b * NN;
    const int jlo = js * (NN / JSPLIT);

    for (int jt = 0; jt < NN / JSPLIT / JT; ++jt) {   // 8 tiles
        const int j0 = jlo + jt * JT;

        // ---- Phase A ----
        const float s2v = s2B[j0 + lane];
        int av[8];
        #pragma unroll
        for (int k = 0; k < 8; ++k)
            av[k] = adj[adj_base + (long)(wv + 4 * k) * NN + j0 + lane];
        #pragma unroll
        for (int k = 0; k < 8; ++k) {
            const int r = wv + 4 * k;
            float e = s1_lds[r] + s2v;
            e = e > 0.f ? e : ALPHA * e;
            const float p = (av[k] != 0) ? __expf(e) : 0.f;
            p_lds[r * JT + lane] = p;
            lacc[k] += p;
        }
        __syncthreads();

        // ---- Phase B: acc += P_tile @ Wh_tile ----
        const float* wp = WhB + (long)j0 * OUT_DIM + d0;
        #pragma unroll 4
        for (int j = 0; j < JT; j += 4) {
            const float4 p0 = *(const float4*)&p_lds[r0 * JT + j];
            const float4 p1 = *(const float4*)&p_lds[(r0 + 1) * JT + j];
            const float4 w0 = *(const float4*)&wp[(long)(j + 0) * OUT_DIM];
            const float4 w1 = *(const float4*)&wp[(long)(j + 1) * OUT_DIM];
            const float4 w2 = *(const float4*)&wp[(long)(j + 2) * OUT_DIM];
            const float4 w3 = *(const float4*)&wp[(long)(j + 3) * OUT_DIM];
            acc0[0] += p0.x * w0.x + p0.y * w1.x + p0.z * w2.x + p0.w * w3.x;
            acc0[1] += p0.x * w0.y + p0.y * w1.y + p0.z * w2.y + p0.w * w3.y;
            acc0[2] += p0.x * w0.z + p0.y * w1.z + p0.z * w2.z + p0.w * w3.z;
            acc0[3] += p0.x * w0.w + p0.y * w1.w + p0.z * w2.w + p0.w * w3.w;
            acc1[0] += p1.x * w0.x + p1.y * w1.x + p1.z * w2.x + p1.w * w3.x;
            acc1[1] += p1.x * w0.y + p1.y * w1.y + p1.z * w2.y + p1.w * w3.y;
            acc1[2] += p1.x * w0.z + p1.y * w1.z + p1.z * w2.z + p1.w * w3.z;
            acc1[3] += p1.x * w0.w + p1.y * w1.w + p1.z * w2.w + p1.w * w3.w;
        }
        __syncthreads();
    }

    // ---- l: reduce across lanes once, one atomic per row ----
    #pragma unroll
    for (int k = 0; k < 8; ++k) {
        float s = lacc[k];
        #pragma unroll
        for (int off = 32; off > 0; off >>= 1) s += __shfl_xor(s, off, 64);
        if (lane == 0) atomicAdd(&l[b * NN + i0 + wv + 4 * k], s);
    }

    // ---- out partials ----
    const long ob = (long)(b * NN + i0 + r0) * OUT_DIM + d0;
    #pragma unroll
    for (int q = 0; q < 4; ++q) atomicAdd(&out[ob + q], acc0[q]);
    #pragma unroll
    for (int q = 0; q < 4; ++q) atomicAdd(&out[ob + OUT_DIM + q], acc1[q]);
}

// ---------------------------------------------------------------------------
// Kernel 3: out[i][:] /= l[i]   (in place, float4)
// ---------------------------------------------------------------------------
__global__ __launch_bounds__(256) void finalize_kernel(float* __restrict__ out,
                                                       const float* __restrict__ l) {
    const int idx = blockIdx.x * 256 + threadIdx.x;   // over 16384*16 float4s
    const int row = idx >> 4;
    const float inv = 1.f / l[row];
    float4* o4 = (float4*)out;
    float4 v = o4[idx];
    v.x *= inv; v.y *= inv; v.z *= inv; v.w *= inv;
    o4[idx] = v;
}

// ---------------------------------------------------------------------------
extern "C" void kernel_launch(void* const* d_in, const int* in_sizes, int n_in,
                              void* d_out, int out_size, void* d_ws, size_t ws_size,
                              hipStream_t stream) {
    const float* h   = (const float*)d_in[0];
    const int*   adj = (const int*)d_in[1];
    const float* W   = (const float*)d_in[2];
    const float* a   = (const float*)d_in[3];
    float* out = (float*)d_out;

    float* Wh = (float*)d_ws;                  // 16384*64 f32 = 4 MB
    float* s1 = Wh + (long)NB * NN * OUT_DIM;  // 16384 f32
    float* s2 = s1 + NB * NN;                  // 16384 f32
    float* l  = s2 + NB * NN;                  // 16384 f32

    hipMemsetAsync(out, 0, (size_t)NB * NN * OUT_DIM * sizeof(float), stream);
    hipMemsetAsync(l, 0, (size_t)NB * NN * sizeof(float), stream);

    wh_kernel<<<NB * NN / 16, 256, 0, stream>>>(h, W, a, Wh, s1, s2);
    attn_kernel<<<NB * (NN / IT) * JSPLIT, 256, 0, stream>>>(adj, Wh, s1, s2, out, l);
    finalize_kernel<<<NB * NN * OUT_DIM / 4 / 256, 256, 0, stream>>>(out, l);
}

// Round 3
// 420.221 us; speedup vs baseline: 1.0406x; 1.0406x over previous
//
#include <hip/hip_runtime.h>
#include <math.h>

#define NB 8
#define NN 2048
#define IN_DIM 256
#define OUT_DIM 64
#define ALPHA 0.2f
#define IT 32
#define JT 64
#define JSPLIT 4
#define PSTRIDE 68   // 16B-aligned pad; r0*68%32 = r0*4 -> rows hit distinct banks

// CK/AITER-style LDS-only barrier: does NOT drain vmcnt, so prefetched
// global loads stay in flight across the workgroup barrier.
__device__ __forceinline__ void sync_after_lds_write() {
    asm volatile("s_waitcnt lgkmcnt(0)\n\ts_barrier" ::: "memory");
}
__device__ __forceinline__ void sync_plain() {
    // phase-B ds_read results are consumed (lgkm waited) before their use;
    // barrier only orders waves.
    asm volatile("s_barrier" ::: "memory");
}

// ---------------------------------------------------------------------------
// Kernel 1: Wh = h @ W, s1 = Wh@a1, s2 = Wh@a2.
// 4096 blocks (16/CU). thread=(row,d): d=lane, wave owns one row.
// h read as wave-uniform float4 broadcast (1 txn, L1); W coalesced L1/L2-hot.
// Two acc chains for ILP; epilogue shuffle-reduces s1/s2 per row.
// ---------------------------------------------------------------------------
__global__ __launch_bounds__(256) void wh_kernel(const float* __restrict__ h,
                                                 const float* __restrict__ W,
                                                 const float* __restrict__ a,
                                                 float* __restrict__ Wh,
                                                 float* __restrict__ s1,
                                                 float* __restrict__ s2) {
    const int t = threadIdx.x;
    const int d = t & 63;
    const int row = blockIdx.x * 4 + (t >> 6);
    const float* __restrict__ hp = h + (long)row * IN_DIM;

    float acc0 = 0.f, acc1 = 0.f;
    #pragma unroll 4
    for (int k = 0; k < IN_DIM; k += 8) {
        const float4 ha = *(const float4*)(hp + k);
        const float4 hb = *(const float4*)(hp + k + 4);
        acc0 += ha.x * W[(k + 0) * OUT_DIM + d];
        acc1 += ha.y * W[(k + 1) * OUT_DIM + d];
        acc0 += ha.z * W[(k + 2) * OUT_DIM + d];
        acc1 += ha.w * W[(k + 3) * OUT_DIM + d];
        acc0 += hb.x * W[(k + 4) * OUT_DIM + d];
        acc1 += hb.y * W[(k + 5) * OUT_DIM + d];
        acc0 += hb.z * W[(k + 6) * OUT_DIM + d];
        acc1 += hb.w * W[(k + 7) * OUT_DIM + d];
    }
    const float whv = acc0 + acc1;
    Wh[(long)row * OUT_DIM + d] = whv;

    float v1 = whv * a[d];
    float v2 = whv * a[OUT_DIM + d];
    #pragma unroll
    for (int off = 32; off > 0; off >>= 1) {
        v1 += __shfl_xor(v1, off, 64);
        v2 += __shfl_xor(v2, off, 64);
    }
    if (d == 0) { s1[row] = v1; s2[row] = v2; }
}

// ---------------------------------------------------------------------------
// Kernel 2: fused masked-softmax + P@Wh (no max subtraction: scores bounded).
// Grid NB*64*JSPLIT = 2048. Software-pipelined: adj/s2 for tile jt+1 are
// prefetched into VGPRs right after the phase-A barrier, so their HBM latency
// is hidden under phase B's FMA loop. LDS-only barriers keep them in flight.
// Partials (out, l) written to ws per jsplit; finalize kernel reduces.
// ---------------------------------------------------------------------------
__global__ __launch_bounds__(256) void attn_kernel(const int* __restrict__ adj,
                                                   const float* __restrict__ Wh,
                                                   const float* __restrict__ s1,
                                                   const float* __restrict__ s2,
                                                   float* __restrict__ part,
                                                   float* __restrict__ lpart) {
    __shared__ float p_lds[IT * PSTRIDE];
    __shared__ float s1_lds[IT];

    const int t = threadIdx.x;
    const int bid = blockIdx.x;
    const int js = bid & (JSPLIT - 1);
    const int it = (bid >> 2) & 63;
    const int b  = bid >> 8;
    const int i0 = it * IT;

    if (t < IT) s1_lds[t] = s1[b * NN + i0 + t];
    __syncthreads();

    const int lane = t & 63;
    const int wv   = t >> 6;
    const int r0   = (t >> 4) << 1;           // phase-B rows r0, r0+1
    const int d0   = (t & 15) << 2;           // phase-B cols d0..d0+3

    float acc0[4] = {0.f, 0.f, 0.f, 0.f};
    float acc1[4] = {0.f, 0.f, 0.f, 0.f};
    float lacc[8] = {0.f, 0.f, 0.f, 0.f, 0.f, 0.f, 0.f, 0.f};

    const long adj_base = (long)b * NN * NN + (long)i0 * NN + lane;
    const float* s2B = s2 + b * NN + lane;
    const float* WhB = Wh + (long)b * NN * OUT_DIM + d0;
    const int jlo = js * (NN / JSPLIT);

    // prologue: prefetch tile 0
    int av[8];
    float s2v = s2B[jlo];
    #pragma unroll
    for (int k = 0; k < 8; ++k)
        av[k] = __builtin_nontemporal_load(&adj[adj_base + (long)(wv + 4 * k) * NN + jlo]);

    for (int jt = 0; jt < NN / JSPLIT / JT; ++jt) {   // 8 tiles
        const int j0 = jlo + jt * JT;

        // ---- Phase A: p from prefetched av/s2v ----
        #pragma unroll
        for (int k = 0; k < 8; ++k) {
            const int r = wv + 4 * k;
            float e = s1_lds[r] + s2v;
            e = e > 0.f ? e : ALPHA * e;
            const float p = (av[k] != 0) ? __expf(e) : 0.f;
            p_lds[r * PSTRIDE + lane] = p;    // contiguous lanes: conflict-free
            lacc[k] += p;
        }
        sync_after_lds_write();

        // ---- prefetch tile jt+1 (stays in flight through phase B) ----
        const int j0n = jlo + (jt < 7 ? jt + 1 : jt) * JT;
        s2v = s2B[j0n];
        #pragma unroll
        for (int k = 0; k < 8; ++k)
            av[k] = __builtin_nontemporal_load(&adj[adj_base + (long)(wv + 4 * k) * NN + j0n]);

        // ---- Phase B: acc += P_tile @ Wh_tile ----
        const float* wp = WhB + (long)j0 * OUT_DIM;
        #pragma unroll 4
        for (int j = 0; j < JT; j += 4) {
            const float4 p0 = *(const float4*)&p_lds[r0 * PSTRIDE + j];
            const float4 p1 = *(const float4*)&p_lds[(r0 + 1) * PSTRIDE + j];
            const float4 w0 = *(const float4*)&wp[(long)(j + 0) * OUT_DIM];
            const float4 w1 = *(const float4*)&wp[(long)(j + 1) * OUT_DIM];
            const float4 w2 = *(const float4*)&wp[(long)(j + 2) * OUT_DIM];
            const float4 w3 = *(const float4*)&wp[(long)(j + 3) * OUT_DIM];
            acc0[0] += p0.x * w0.x + p0.y * w1.x + p0.z * w2.x + p0.w * w3.x;
            acc0[1] += p0.x * w0.y + p0.y * w1.y + p0.z * w2.y + p0.w * w3.y;
            acc0[2] += p0.x * w0.z + p0.y * w1.z + p0.z * w2.z + p0.w * w3.z;
            acc0[3] += p0.x * w0.w + p0.y * w1.w + p0.z * w2.w + p0.w * w3.w;
            acc1[0] += p1.x * w0.x + p1.y * w1.x + p1.z * w2.x + p1.w * w3.x;
            acc1[1] += p1.x * w0.y + p1.y * w1.y + p1.z * w2.y + p1.w * w3.y;
            acc1[2] += p1.x * w0.z + p1.y * w1.z + p1.z * w2.z + p1.w * w3.z;
            acc1[3] += p1.x * w0.w + p1.y * w1.w + p1.z * w2.w + p1.w * w3.w;
        }
        sync_plain();
    }

    // ---- epilogue: l partial (one writer per row) + out partials ----
    #pragma unroll
    for (int k = 0; k < 8; ++k) {
        float s = lacc[k];
        #pragma unroll
        for (int off = 32; off > 0; off >>= 1) s += __shfl_xor(s, off, 64);
        if (lane == 0) lpart[js * (NB * NN) + b * NN + i0 + wv + 4 * k] = s;
    }
    float* op = part + (long)js * (NB * NN * OUT_DIM)
                     + (long)(b * NN + i0 + r0) * OUT_DIM + d0;
    *(float4*)op = make_float4(acc0[0], acc0[1], acc0[2], acc0[3]);
    *(float4*)(op + OUT_DIM) = make_float4(acc1[0], acc1[1], acc1[2], acc1[3]);
}

// ---------------------------------------------------------------------------
// Kernel 3: out = (sum_js part) / (sum_js lpart), float4, fully coalesced.
// ---------------------------------------------------------------------------
__global__ __launch_bounds__(256) void finalize_kernel(const float* __restrict__ part,
                                                       const float* __restrict__ lpart,
                                                       float* __restrict__ out) {
    const int idx = blockIdx.x * 256 + threadIdx.x;   // float4 index, 262144
    const int row = idx >> 4;
    float l = 0.f;
    #pragma unroll
    for (int s = 0; s < JSPLIT; ++s) l += lpart[s * (NB * NN) + row];
    float4 v = make_float4(0.f, 0.f, 0.f, 0.f);
    const float4* p4 = (const float4*)part;
    #pragma unroll
    for (int s = 0; s < JSPLIT; ++s) {
        const float4 p = p4[(long)s * (NB * NN * OUT_DIM / 4) + idx];
        v.x += p.x; v.y += p.y; v.z += p.z; v.w += p.w;
    }
    const float inv = 1.f / l;
    v.x *= inv; v.y *= inv; v.z *= inv; v.w *= inv;
    ((float4*)out)[idx] = v;
}

// ---------------------------------------------------------------------------
extern "C" void kernel_launch(void* const* d_in, const int* in_sizes, int n_in,
                              void* d_out, int out_size, void* d_ws, size_t ws_size,
                              hipStream_t stream) {
    const float* h   = (const float*)d_in[0];
    const int*   adj = (const int*)d_in[1];
    const float* W   = (const float*)d_in[2];
    const float* a   = (const float*)d_in[3];
    float* out = (float*)d_out;

    float* Wh    = (float*)d_ws;                        // 1M f32 = 4 MB
    float* s1    = Wh + (long)NB * NN * OUT_DIM;        // 16K f32
    float* s2    = s1 + NB * NN;                        // 16K f32
    float* lpart = s2 + NB * NN;                        // 64K f32
    float* part  = lpart + JSPLIT * NB * NN;            // 4M f32 = 16 MB

    wh_kernel<<<NB * NN / 4, 256, 0, stream>>>(h, W, a, Wh, s1, s2);
    attn_kernel<<<NB * (NN / IT) * JSPLIT, 256, 0, stream>>>(adj, Wh, s1, s2, part, lpart);
    finalize_kernel<<<NB * NN * OUT_DIM / 4 / 256, 256, 0, stream>>>(part, lpart, out);
}

// Round 4
// 231.478 us; speedup vs baseline: 1.8890x; 1.8154x over previous
//
#include <hip/hip_runtime.h>
#include <math.h>

#define NB 8
#define NN 2048
#define IN_DIM 256
#define OUT_DIM 64
#define ALPHA 0.2f
#define JSPLIT 4

typedef __attribute__((ext_vector_type(8))) short bf16x8;
typedef __attribute__((ext_vector_type(4))) float f32x4;

// float -> bf16 (RNE), bit trick (no NaN inputs here)
__device__ __forceinline__ unsigned short f2bf(float x) {
    union { float f; unsigned u; } v; v.f = x;
    unsigned r = v.u + 0x7FFF + ((v.u >> 16) & 1);
    return (unsigned short)(r >> 16);
}

// ---------------------------------------------------------------------------
// Kernel 1: Wh = h@W via bf16 MFMA. Outputs: Whbt (bf16, layout [b][d][j] so
// kernel-2 B-frags are 16B contiguous per lane), s1 = Wh@a1, s2 = Wh@a2.
// W staged once per block into LDS TRANSPOSED (Wt[n][k], pad 264) so B-frag
// reads are ds_read_b128.  NO wave-uniform global vector loads anywhere
// (suspected 64x replication made the old wh ~180us).
// Grid 256 blocks x 256 thr; wave = one 16-row i-tile, block = 64 rows.
// ---------------------------------------------------------------------------
#define WT_STRIDE 264   // bf16 elems; 528B rows (16B aligned); 4n mod 32 -> 2-way only
__global__ __launch_bounds__(256) void wh_kernel(const float* __restrict__ h,
                                                 const float* __restrict__ W,
                                                 const float* __restrict__ a,
                                                 unsigned short* __restrict__ Whbt,
                                                 float* __restrict__ s1,
                                                 float* __restrict__ s2) {
    __shared__ unsigned short Wt[OUT_DIM * WT_STRIDE];   // ~33 KB
    const int t = threadIdx.x;

    // stage W (coalesced f32 reads) -> Wt[n][k] bf16
    #pragma unroll 8
    for (int rep = 0; rep < 64; ++rep) {
        const int id = rep * 256 + t;          // 0..16383
        const int k = id >> 6, n = id & 63;
        Wt[n * WT_STRIDE + k] = f2bf(W[id]);
    }
    __syncthreads();

    const int lane = t & 63, wv = t >> 6;
    const int m = lane & 15, quad = lane >> 4;
    const long gr0 = (long)(blockIdx.x * 4 + wv) * 16;   // global row base

    f32x4 acc[4];
    #pragma unroll
    for (int nt = 0; nt < 4; ++nt) acc[nt] = (f32x4){0.f, 0.f, 0.f, 0.f};

    #pragma unroll
    for (int ks = 0; ks < 8; ++ks) {
        const int k0 = ks * 32;
        // A-frag: h[i = gr0+m][k0 + quad*8 .. +7]  (per-lane distinct, 32B)
        const float* hp = h + (gr0 + m) * IN_DIM + k0 + quad * 8;
        const float4 ha = *(const float4*)hp;
        const float4 hb = *(const float4*)(hp + 4);
        bf16x8 af;
        af[0] = (short)f2bf(ha.x); af[1] = (short)f2bf(ha.y);
        af[2] = (short)f2bf(ha.z); af[3] = (short)f2bf(ha.w);
        af[4] = (short)f2bf(hb.x); af[5] = (short)f2bf(hb.y);
        af[6] = (short)f2bf(hb.z); af[7] = (short)f2bf(hb.w);
        #pragma unroll
        for (int nt = 0; nt < 4; ++nt) {
            // B-frag: Wt[n = nt*16+m][k0 + quad*8 .. +7] -> ds_read_b128
            const bf16x8 bf_ = *(const bf16x8*)(const void*)
                &Wt[(nt * 16 + m) * WT_STRIDE + k0 + quad * 8];
            acc[nt] = __builtin_amdgcn_mfma_f32_16x16x32_bf16(af, bf_, acc[nt], 0, 0, 0);
        }
    }

    // ---- epilogue.  C layout: col=lane&15 (d within tile), row=quad*4+reg (i) ----
    const int b  = (int)(gr0 >> 11);
    const int ib = (int)(gr0 & 2047);          // within-batch row base

    // Whbt[b][d][j]: pack 4 consecutive i (regs) as ushort4
    #pragma unroll
    for (int nt = 0; nt < 4; ++nt) {
        ushort4 w4;
        w4.x = f2bf(acc[nt][0]); w4.y = f2bf(acc[nt][1]);
        w4.z = f2bf(acc[nt][2]); w4.w = f2bf(acc[nt][3]);
        *(ushort4*)&Whbt[((long)(b * OUT_DIM + nt * 16 + m) << 11) + ib + quad * 4] = w4;
    }

    // s1/s2: per-lane partial over its 4 cols, reduce across the 16-lane col group
    float a1v[4], a2v[4];
    #pragma unroll
    for (int nt = 0; nt < 4; ++nt) {
        a1v[nt] = a[nt * 16 + m];
        a2v[nt] = a[OUT_DIM + nt * 16 + m];
    }
    #pragma unroll
    for (int reg = 0; reg < 4; ++reg) {
        float p1 = 0.f, p2 = 0.f;
        #pragma unroll
        for (int nt = 0; nt < 4; ++nt) {
            p1 += acc[nt][reg] * a1v[nt];
            p2 += acc[nt][reg] * a2v[nt];
        }
        #pragma unroll
        for (int off = 1; off < 16; off <<= 1) {   // lanes quad*16+m, m-group
            p1 += __shfl_xor(p1, off, 64);
            p2 += __shfl_xor(p2, off, 64);
        }
        if (m == 0) {
            s1[gr0 + quad * 4 + reg] = p1;
            s2[gr0 + quad * 4 + reg] = p2;
        }
    }
}

// ---------------------------------------------------------------------------
// Kernel 2: masked softmax (no max-subtraction; scores bounded) + P@Wh via
// bf16 MFMA.  Each WAVE is fully independent: own 16-row i-tile, own private
// LDS p-buffer (no __syncthreads at all).  Per 32-j step:
//   phase A: 8 coalesced adj loads (lane = 2 rows x 32 j), exp, bf16 p -> LDS
//   phase B: 1 ds_read_b128 A-frag + 4 global 16B B-frags (Whbt, L2-hot)
//            + 4 x mfma_f32_16x16x32_bf16
// Grid: NB * (NN/64) * JSPLIT = 1024 blocks x 4 waves (16 waves/CU).
// Partials to part/lpart; finalize divides.
// ---------------------------------------------------------------------------
#define PSTR 40   // bf16 elems; 80B rows (16B aligned); <=2-way banks both phases
__global__ __launch_bounds__(256) void attn_kernel(const int* __restrict__ adj,
                                                   const unsigned short* __restrict__ Whbt,
                                                   const float* __restrict__ s1,
                                                   const float* __restrict__ s2,
                                                   float* __restrict__ part,
                                                   float* __restrict__ lpart) {
    __shared__ unsigned short p_all[4][16 * PSTR];   // 4 waves x 1280B, wave-private

    const int t = threadIdx.x, lane = t & 63, wv = t >> 6;
    unsigned short* p_lds = &p_all[wv][0];

    const int bid = blockIdx.x;
    const int js  = bid & (JSPLIT - 1);
    const int itg = (bid >> 2) & 31;
    const int b   = bid >> 7;
    const int i0  = itg * 64 + wv * 16;       // within-batch row base (16 rows)
    const int jlo = js * (NN / JSPLIT);       // 512-wide j slice

    const int rhalf = lane >> 5, jj = lane & 31;   // phase-A map: 2 rows x 32 j
    const int m = lane & 15, quad = lane >> 4;     // MFMA lane map

    float s1r[8];
    #pragma unroll
    for (int k = 0; k < 8; ++k) s1r[k] = s1[b * NN + i0 + rhalf + 2 * k];

    f32x4 acc[4];
    #pragma unroll
    for (int nt = 0; nt < 4; ++nt) acc[nt] = (f32x4){0.f, 0.f, 0.f, 0.f};
    float lacc[8] = {0.f, 0.f, 0.f, 0.f, 0.f, 0.f, 0.f, 0.f};

    const int* adjp = adj + (long)b * NN * NN + (long)(i0 + rhalf) * NN + jlo + jj;
    const unsigned short* wbase = Whbt + ((long)(b * OUT_DIM) << 11) + jlo;
    const float* s2p = s2 + b * NN + jlo + jj;

    // prefetch step 0
    int av[8];
    #pragma unroll
    for (int k = 0; k < 8; ++k)
        av[k] = __builtin_nontemporal_load(adjp + (long)(2 * k) * NN);

    for (int ks = 0; ks < 16; ++ks) {
        const int j0 = ks * 32;

        // B-frags for this step (independent of phase A; issue early)
        bf16x8 bfr[4];
        #pragma unroll
        for (int nt = 0; nt < 4; ++nt)
            bfr[nt] = *(const bf16x8*)(const void*)
                &wbase[((long)(nt * 16 + m) << 11) + j0 + quad * 8];

        // phase A: p for 16 rows x 32 j
        const float s2v = s2p[j0];
        #pragma unroll
        for (int k = 0; k < 8; ++k) {
            float e = s1r[k] + s2v;
            e = e > 0.f ? e : ALPHA * e;
            const float p = (av[k] != 0) ? __expf(e) : 0.f;
            lacc[k] += p;
            p_lds[(rhalf + 2 * k) * PSTR + jj] = f2bf(p);
        }

        // prefetch next step's adj (in flight through MFMA phase)
        const int jn = (ks < 15) ? j0 + 32 : j0;
        #pragma unroll
        for (int k = 0; k < 8; ++k)
            av[k] = __builtin_nontemporal_load(adjp + (long)(2 * k) * NN + jn);

        // wave-private LDS round-trip: drain writes, no barrier needed
        asm volatile("s_waitcnt lgkmcnt(0)" ::: "memory");

        // phase B: A-frag + 4 MFMA
        const bf16x8 af = *(const bf16x8*)(const void*)&p_lds[m * PSTR + quad * 8];
        #pragma unroll
        for (int nt = 0; nt < 4; ++nt)
            acc[nt] = __builtin_amdgcn_mfma_f32_16x16x32_bf16(af, bfr[nt], acc[nt], 0, 0, 0);
    }

    // ---- epilogue: l partials (reduce over 32 j-lanes within each half) ----
    #pragma unroll
    for (int k = 0; k < 8; ++k) {
        float s = lacc[k];
        #pragma unroll
        for (int off = 1; off < 32; off <<= 1) s += __shfl_xor(s, off, 64);
        if (jj == 0)
            lpart[js * (NB * NN) + b * NN + i0 + rhalf + 2 * k] = s;
    }

    // ---- out partials.  C layout: i = i0+quad*4+reg, d = nt*16+m ----
    float* pp = part + (long)js * ((long)NB * NN * OUT_DIM)
                     + ((long)(b * NN + i0) << 6);
    #pragma unroll
    for (int nt = 0; nt < 4; ++nt)
        #pragma unroll
        for (int reg = 0; reg < 4; ++reg)
            pp[(quad * 4 + reg) * OUT_DIM + nt * 16 + m] = acc[nt][reg];
}

// ---------------------------------------------------------------------------
// Kernel 3: out = (sum_js part) / (sum_js lpart), float4 coalesced.
// ---------------------------------------------------------------------------
__global__ __launch_bounds__(256) void finalize_kernel(const float* __restrict__ part,
                                                       const float* __restrict__ lpart,
                                                       float* __restrict__ out) {
    const int idx = blockIdx.x * 256 + threadIdx.x;   // float4 index
    const int row = idx >> 4;
    float l = 0.f;
    #pragma unroll
    for (int s = 0; s < JSPLIT; ++s) l += lpart[s * (NB * NN) + row];
    float4 v = make_float4(0.f, 0.f, 0.f, 0.f);
    const float4* p4 = (const float4*)part;
    #pragma unroll
    for (int s = 0; s < JSPLIT; ++s) {
        const float4 p = p4[(long)s * ((long)NB * NN * OUT_DIM / 4) + idx];
        v.x += p.x; v.y += p.y; v.z += p.z; v.w += p.w;
    }
    const float inv = 1.f / l;
    v.x *= inv; v.y *= inv; v.z *= inv; v.w *= inv;
    ((float4*)out)[idx] = v;
}

// ---------------------------------------------------------------------------
extern "C" void kernel_launch(void* const* d_in, const int* in_sizes, int n_in,
                              void* d_out, int out_size, void* d_ws, size_t ws_size,
                              hipStream_t stream) {
    const float* h   = (const float*)d_in[0];
    const int*   adj = (const int*)d_in[1];
    const float* W   = (const float*)d_in[2];
    const float* a   = (const float*)d_in[3];
    float* out = (float*)d_out;

    float* s1    = (float*)d_ws;                         // 16K f32
    float* s2    = s1 + NB * NN;                         // 16K f32
    float* lpart = s2 + NB * NN;                         // 64K f32
    float* part  = lpart + JSPLIT * NB * NN;             // 4M f32 = 16 MB
    unsigned short* Whbt = (unsigned short*)(part + (long)JSPLIT * NB * NN * OUT_DIM); // 1M bf16 = 2 MB

    wh_kernel<<<NB * NN / 64, 256, 0, stream>>>(h, W, a, Whbt, s1, s2);
    attn_kernel<<<NB * (NN / 64) * JSPLIT, 256, 0, stream>>>(adj, Whbt, s1, s2, part, lpart);
    finalize_kernel<<<NB * NN * OUT_DIM / 4 / 256, 256, 0, stream>>>(part, lpart, out);
}